// Round 15
// baseline (173.505 us; speedup 1.0000x reference)
//
#include <hip/hip_runtime.h>
#include <hip/hip_bf16.h>

#define T_SEQ 2048
#define NHEAD 16
#define HDIM  64
#define CDIM  1024

typedef __attribute__((ext_vector_type(8))) short bf16x8;
typedef __attribute__((ext_vector_type(4))) short bf16x4;
typedef __attribute__((ext_vector_type(4))) float f32x4;

__device__ __forceinline__ unsigned short f2bf(float f) {
  union { __hip_bfloat16 h; unsigned short u; } c;
  c.h = __float2bfloat16(f);
  return c.u;
}

#define GLD16(g, l) __builtin_amdgcn_global_load_lds( \
  (const __attribute__((address_space(1))) void*)(g), \
  (__attribute__((address_space(3))) void*)(l), 16, 0, 0)

// ---------------- merged prep: x->bf16 cast + both weight transposes ----------------
__global__ void prep_all(const float* __restrict__ x, const float* __restrict__ wa,
                         const float* __restrict__ wp, unsigned short* __restrict__ xb,
                         unsigned short* __restrict__ wat, unsigned short* __restrict__ wpt) {
  __shared__ float tile[32][33];
  const int bid = blockIdx.x;
  if (bid < 8192) {
    const int i = bid * 256 + threadIdx.x;
    const float4 v = ((const float4*)x)[i];
    ushort4 o;
    o.x = f2bf(v.x); o.y = f2bf(v.y); o.z = f2bf(v.z); o.w = f2bf(v.w);
    ((ushort4*)xb)[i] = o;
    return;
  }
  const float* in; unsigned short* out; int R, C, bx, by;
  if (bid < 11264) { in = wa; out = wat; R = 1024; C = 3072; bx = (bid - 8192) % 96; by = (bid - 8192) / 96; }
  else             { in = wp; out = wpt; R = 1024; C = 1024; bx = (bid - 11264) % 32; by = (bid - 11264) / 32; }
  const int tx = threadIdx.x & 31, ty = threadIdx.x >> 5;
  const int c0 = bx * 32, r0 = by * 32;
#pragma unroll
  for (int i = 0; i < 32; i += 8)
    tile[ty + i][tx] = in[(size_t)(r0 + ty + i) * C + c0 + tx];
  __syncthreads();
#pragma unroll
  for (int i = 0; i < 32; i += 8)
    out[(size_t)(c0 + ty + i) * R + r0 + tx] = f2bf(tile[tx][ty + i]);
}

// ---------------- bf16 MFMA GEMM (round-14 proven: BK=64, slot-XOR swizzle) ----------------
template<int OUTF32>
__global__ __launch_bounds__(256, 2)
void gemm_bt(const unsigned short* __restrict__ A, const unsigned short* __restrict__ BT,
             const float* __restrict__ bias, void* __restrict__ outp,
             int M, int N, int K) {
  const int tid = threadIdx.x;
  const int w = tid >> 6, lane = tid & 63;
  const int lg = lane >> 4, l15 = lane & 15;
  const int wr = w >> 1, wc = w & 1;

  const int nb = gridDim.x * gridDim.y;
  const int fid = blockIdx.y * gridDim.x + blockIdx.x;
  const int swz = (fid & 7) * (nb >> 3) + (fid >> 3);
  const int n0 = (swz % gridDim.x) * 128, m0 = (swz / gridDim.x) * 128;

  __shared__ unsigned short As[128 * 64];
  __shared__ unsigned short Bs[128 * 64];

  f32x4 acc[4][4] = {};

  for (int k0 = 0; k0 < K; k0 += 64) {
    __syncthreads();
#pragma unroll
    for (int i = 0; i < 4; ++i) {
      const int cb = i * 256 + w * 64;
      const int c  = cb + lane;
      const int row = c >> 3, s = c & 7;
      const int sg = s ^ (row & 7);
      GLD16(A  + (size_t)(m0 + row) * K + k0 + sg * 8, (char*)As + cb * 16);
      GLD16(BT + (size_t)(n0 + row) * K + k0 + sg * 8, (char*)Bs + cb * 16);
    }
    __syncthreads();
#pragma unroll
    for (int ks = 0; ks < 2; ++ks) {
      bf16x8 af[4], bfr[4];
#pragma unroll
      for (int mt = 0; mt < 4; ++mt) {
        const int row = wr * 64 + mt * 16 + l15;
        af[mt] = *(const bf16x8*)&As[row * 64 + (((ks * 4 + lg) ^ (l15 & 7)) << 3)];
      }
#pragma unroll
      for (int nt = 0; nt < 4; ++nt) {
        const int row = wc * 64 + nt * 16 + l15;
        bfr[nt] = *(const bf16x8*)&Bs[row * 64 + (((ks * 4 + lg) ^ (l15 & 7)) << 3)];
      }
#pragma unroll
      for (int mt = 0; mt < 4; ++mt)
#pragma unroll
        for (int nt = 0; nt < 4; ++nt)
          acc[mt][nt] = __builtin_amdgcn_mfma_f32_16x16x32_bf16(af[mt], bfr[nt], acc[mt][nt], 0, 0, 0);
    }
  }

#pragma unroll
  for (int mt = 0; mt < 4; ++mt) {
#pragma unroll
    for (int nt = 0; nt < 4; ++nt) {
      const int col = n0 + wc * 64 + nt * 16 + l15;
      const float bv = bias[col];
#pragma unroll
      for (int j = 0; j < 4; ++j) {
        const int row = m0 + wr * 64 + mt * 16 + lg * 4 + j;
        const float v = acc[mt][nt][j] + bv;
        if (OUTF32) ((float*)outp)[(size_t)row * N + col] = v;
        else ((unsigned short*)outp)[(size_t)row * N + col] = f2bf(v);
      }
    }
  }
}

// ---------------- causal flash attention v12: v5 + triple-buffer + counted vmcnt ----------------
// v5 structure (8 waves x 16 q-rows, {p,15-p} pairing, 34 uniform iters) with
// prefetch depth 2: iter t issues K(t+2)+V(t+2) (3 vmem/wave), computes tile t,
// VWRITEs t+1, then waits vmcnt(3) (leaves exactly this iter's issues in flight)
// instead of __syncthreads' vmcnt(0) drain. FIFO: K(t+1)/V(t+1) are older than
// the 3 outstanding => provably landed. Static V-reg ping-pong via x2 unroll.
#define EXPC 0.18033688f   /* 0.125 * log2(e) */
__global__ __launch_bounds__(512, 4)
void attn_causal12(const unsigned short* __restrict__ qkv, unsigned short* __restrict__ att) {
  const int tid = threadIdx.x;
  const int w = tid >> 6, lane = tid & 63;
  const int lg = lane >> 4, l15 = lane & 15;

  const int fid = blockIdx.x;                   // 0..511
  const int f2 = (fid & 7) * 64 + (fid >> 3);   // XCD-chunked remap (bijective)
  const int pair = f2 & 7, bh = f2 >> 3;
  const int b = bh >> 4, h = bh & 15;

  __shared__ unsigned short Kl[3][2][64][32];   // 24 KB, slot+row permuted
  __shared__ unsigned short Vt[3][64][64];      // 24 KB, chunk-swizzled

  const unsigned short* base = qkv + (size_t)b * T_SEQ * 3072;

  auto STAGE_K = [&](int kv0, int buf) {
    const int c = tid;                          // 512 chunks of 16B, 1 gld_lds/thread
    const int kc = c >> 8, slot = (c >> 2) & 63;
    const int s2 = (c & 3) ^ ((slot >> 1) & 3);
    const int v = (slot & 35) | ((slot & 8) << 1) | ((slot & 4) << 1) | ((slot & 16) >> 2);
    GLD16(base + (size_t)(kv0 + v) * 3072 + 1024 + h * 64 + kc * 32 + s2 * 8,
          (char*)&Kl[buf][0][0][0] + w * 1024);
  };

  const int vkp = tid >> 4, vd4 = tid & 15;
  auto VLOAD = [&](int kv0, bf16x4& ra, bf16x4& rb) {   // 2 vmem/thread
    const unsigned short* p = base + (size_t)(kv0 + 2 * vkp) * 3072 + 2048 + h * 64 + vd4 * 4;
    ra = *(const bf16x4*)p;
    rb = *(const bf16x4*)(p + 3072);
  };
  auto VWRITE = [&](int buf, bf16x4 ra, bf16x4 rb) {
    const int ch = vkp >> 2, cl = (vkp & 3) * 2;
#pragma unroll
    for (int j = 0; j < 4; ++j) {
      const int r = vd4 * 4 + j;
      const unsigned int u = (unsigned short)ra[j] |
                             ((unsigned int)(unsigned short)rb[j] << 16);
      *(unsigned int*)&Vt[buf][r][((ch ^ (r >> 3) ^ (r & 7)) << 3) + cl] = u;
    }
  };

  bf16x8 ones;
#pragma unroll
  for (int j = 0; j < 8; ++j) ones[j] = (short)0x3F80;   // bf16 1.0

  for (int half = 0; half < 2; ++half) {
    const int qt = half ? (15 - pair) : pair;
    const int q0 = qt << 7;
    const int ntl = (qt + 1) << 1;              // KV64 tiles (always even, >= 2)
    const int qminS = __builtin_amdgcn_readfirstlane(q0 + w * 16);
    const int qme = qminS + l15;

    bf16x8 qf[2];
#pragma unroll
    for (int kc = 0; kc < 2; ++kc)
      qf[kc] = *(const bf16x8*)(base + (size_t)qme * 3072 + h * 64 + kc * 32 + lg * 8);

    f32x4 oacc[4] = {};
    f32x4 lsum = {};
    float m = -1e30f;
    bf16x4 v0a, v0b, v1a, v1b;                  // V-reg ping-pong: V(k) in set k&1

    auto COMPUTE = [&](int t, int bA) {
      const int kv0 = t << 6;
      if (kv0 > qminS + 15) return;             // wave fully masked (scalar)
      const int ksl = (lg ^ ((l15 >> 1) & 3)) * 8;
      f32x4 sc[4];
      __builtin_amdgcn_s_setprio(1);
#pragma unroll
      for (int kg = 0; kg < 4; ++kg) {
        f32x4 s = {};
#pragma unroll
        for (int kc = 0; kc < 2; ++kc) {
          bf16x8 kf = *(const bf16x8*)&Kl[bA][kc][kg * 16 + l15][ksl];
          s = __builtin_amdgcn_mfma_f32_16x16x32_bf16(kf, qf[kc], s, 0, 0, 0);
        }
        sc[kg] = s;
      }
      __builtin_amdgcn_s_setprio(0);

      float sv[4][4];
      if (kv0 + 63 > qminS) {
#pragma unroll
        for (int kg = 0; kg < 4; ++kg) {
          const int colb = kv0 + ((kg >> 1) << 5) + ((kg & 1) << 2) + lg * 8;
#pragma unroll
          for (int j = 0; j < 4; ++j)
            sv[kg][j] = (colb + j <= qme) ? sc[kg][j] : -1e30f;
        }
      } else {
#pragma unroll
        for (int kg = 0; kg < 4; ++kg)
#pragma unroll
          for (int j = 0; j < 4; ++j) sv[kg][j] = sc[kg][j];
      }

      float mx = -1e30f;
#pragma unroll
      for (int kg = 0; kg < 4; ++kg) {
        const float a = fmaxf(sv[kg][0], sv[kg][1]);
        const float c2 = fmaxf(sv[kg][2], sv[kg][3]);
        mx = fmaxf(mx, fmaxf(a, c2));
      }

      if (__any(mx > m + 55.4f)) {
        float mw = fmaxf(mx, __shfl_xor(mx, 16));
        mw = fmaxf(mw, __shfl_xor(mw, 32));
        const float mnew = fmaxf(m, mw);
        const float alc = exp2f((m - mnew) * EXPC);
        m = mnew;
        float alq[4];
#pragma unroll
        for (int j = 0; j < 4; ++j)
          alq[j] = __shfl(alc, (lane & 48) | (lg * 4 + j));
#pragma unroll
        for (int j = 0; j < 4; ++j) {
          lsum[j] *= alq[j];
#pragma unroll
          for (int dt = 0; dt < 4; ++dt) oacc[dt][j] *= alq[j];
        }
      }

      const float mc = m * EXPC;
      bf16x8 pa[2];
#pragma unroll
      for (int kg = 0; kg < 4; ++kg) {
        const int ks = kg >> 1, off = (kg & 1) * 4;
#pragma unroll
        for (int j = 0; j < 4; ++j) {
          const float p = exp2f(__fmaf_rn(sv[kg][j], EXPC, -mc));
          pa[ks][off + j] = (short)f2bf(p);
        }
      }

      __builtin_amdgcn_s_setprio(1);
      lsum = __builtin_amdgcn_mfma_f32_16x16x32_bf16(pa[0], ones, lsum, 0, 0, 0);
      lsum = __builtin_amdgcn_mfma_f32_16x16x32_bf16(pa[1], ones, lsum, 0, 0, 0);
#pragma unroll
      for (int dt = 0; dt < 4; ++dt) {
        f32x4 o = oacc[dt];
        const int d = dt * 16 + l15;
        const int gx = (d >> 3) ^ (d & 7);
#pragma unroll
        for (int ks = 0; ks < 2; ++ks) {
          bf16x8 vb = *(const bf16x8*)&Vt[bA][d][((ks * 4 + lg) ^ gx) << 3];
          o = __builtin_amdgcn_mfma_f32_16x16x32_bf16(pa[ks], vb, o, 0, 0, 0);
        }
        oacc[dt] = o;
      }
      __builtin_amdgcn_s_setprio(0);
    };

    auto TAIL = [&](int t, int bB, bf16x4 wa, bf16x4 wb) {
      if ((t + 1) < ntl) VWRITE(bB, wa, wb);    // compiler drains V(t+1) loads (older than this iter's 3)
      if ((t + 2) < ntl) {                      // this iter issued 3 vmem: leave them in flight
        asm volatile("s_waitcnt vmcnt(3) lgkmcnt(0)" ::: "memory");
      } else {                                  // no prefetch this iter: full drain
        asm volatile("s_waitcnt vmcnt(0) lgkmcnt(0)" ::: "memory");
      }
      __builtin_amdgcn_sched_barrier(0);
      __builtin_amdgcn_s_barrier();
      __builtin_amdgcn_sched_barrier(0);
    };

    // ---- prologue: tiles 0 and 1 ----
    STAGE_K(0, 0);
    VLOAD(0, v0a, v0b);
    VWRITE(0, v0a, v0b);                        // reg-dep drains K(0)+V(0)
    STAGE_K(64, 1);
    VLOAD(64, v1a, v1b);
    asm volatile("s_waitcnt vmcnt(3) lgkmcnt(0)" ::: "memory");  // K(1),V(1) stay in flight
    __builtin_amdgcn_sched_barrier(0);
    __builtin_amdgcn_s_barrier();
    __builtin_amdgcn_sched_barrier(0);

    int bA = 0, bB = 1, bC = 2;
    for (int t = 0; t < ntl; t += 2) {
      if ((t + 2) < ntl) { STAGE_K((t + 2) << 6, bC); VLOAD((t + 2) << 6, v0a, v0b); }
      COMPUTE(t, bA);
      TAIL(t, bB, v1a, v1b);                    // VWRITE(t+1) from set1
      if ((t + 3) < ntl) { STAGE_K((t + 3) << 6, bA); VLOAD((t + 3) << 6, v1a, v1b); }
      COMPUTE(t + 1, bB);
      TAIL(t + 1, bC, v0a, v0b);                // VWRITE(t+2) from set0
      const int nA = bC, nB2 = bA, nC = bB;     // rotate by 2: (A,B,C) <- (C,A,B)
      bA = nA; bB = nB2; bC = nC;
    }

    // ---- epilogue: normalize via rcp, store ----
    f32x4 inv;
#pragma unroll
    for (int j = 0; j < 4; ++j) inv[j] = __builtin_amdgcn_rcpf(lsum[j]);
#pragma unroll
    for (int dt = 0; dt < 4; ++dt)
#pragma unroll
      for (int j = 0; j < 4; ++j) {
        const int q = qminS + lg * 4 + j;
        att[(size_t)(b * T_SEQ + q) * CDIM + h * HDIM + dt * 16 + l15] =
            f2bf(oacc[dt][j] * inv[j]);
      }
  }
}

// ---------------- launcher ----------------
extern "C" void kernel_launch(void* const* d_in, const int* in_sizes, int n_in,
                              void* d_out, int out_size, void* d_ws, size_t ws_size,
                              hipStream_t stream) {
  const float* x      = (const float*)d_in[0];
  const float* w_attn = (const float*)d_in[1];
  const float* b_attn = (const float*)d_in[2];
  const float* w_proj = (const float*)d_in[3];
  const float* b_proj = (const float*)d_in[4];

  char* ws = (char*)d_ws;
  unsigned short* xb  = (unsigned short*)(ws + 0);           // 8192*1024 bf16
  unsigned short* wat = (unsigned short*)(ws + 16777216);    // 3072*1024 bf16 (w_attn^T)
  unsigned short* wpt = (unsigned short*)(ws + 23068672);    // 1024*1024 bf16 (w_proj^T)
  unsigned short* qkv = (unsigned short*)(ws + 25165824);    // 8192*3072 bf16
  unsigned short* att = (unsigned short*)(ws + 75497472);    // 8192*1024 bf16

  prep_all<<<dim3(12288), 256, 0, stream>>>(x, w_attn, w_proj, xb, wat, wpt);
  gemm_bt<0><<<dim3(24, 64), 256, 0, stream>>>(xb, wat, b_attn, (void*)qkv, 8192, 3072, 1024);
  attn_causal12<<<dim3(512), 512, 0, stream>>>(qkv, att);
  gemm_bt<1><<<dim3(8, 64), 256, 0, stream>>>(att, wpt, b_proj, d_out, 8192, 1024, 1024);
}

// Round 16
// 173.334 us; speedup vs baseline: 1.0010x; 1.0010x over previous
//
#include <hip/hip_runtime.h>
#include <hip/hip_bf16.h>

#define T_SEQ 2048
#define NHEAD 16
#define HDIM  64
#define CDIM  1024

typedef __attribute__((ext_vector_type(8))) short bf16x8;
typedef __attribute__((ext_vector_type(4))) short bf16x4;
typedef __attribute__((ext_vector_type(4))) float f32x4;

__device__ __forceinline__ unsigned short f2bf(float f) {
  union { __hip_bfloat16 h; unsigned short u; } c;
  c.h = __float2bfloat16(f);
  return c.u;
}

#define GLD16(g, l) __builtin_amdgcn_global_load_lds( \
  (const __attribute__((address_space(1))) void*)(g), \
  (__attribute__((address_space(3))) void*)(l), 16, 0, 0)

// ---------------- merged prep: x->bf16 cast + both weight transposes ----------------
__global__ void prep_all(const float* __restrict__ x, const float* __restrict__ wa,
                         const float* __restrict__ wp, unsigned short* __restrict__ xb,
                         unsigned short* __restrict__ wat, unsigned short* __restrict__ wpt) {
  __shared__ float tile[32][33];
  const int bid = blockIdx.x;
  if (bid < 8192) {
    const int i = bid * 256 + threadIdx.x;
    const float4 v = ((const float4*)x)[i];
    ushort4 o;
    o.x = f2bf(v.x); o.y = f2bf(v.y); o.z = f2bf(v.z); o.w = f2bf(v.w);
    ((ushort4*)xb)[i] = o;
    return;
  }
  const float* in; unsigned short* out; int R, C, bx, by;
  if (bid < 11264) { in = wa; out = wat; R = 1024; C = 3072; bx = (bid - 8192) % 96; by = (bid - 8192) / 96; }
  else             { in = wp; out = wpt; R = 1024; C = 1024; bx = (bid - 11264) % 32; by = (bid - 11264) / 32; }
  const int tx = threadIdx.x & 31, ty = threadIdx.x >> 5;
  const int c0 = bx * 32, r0 = by * 32;
#pragma unroll
  for (int i = 0; i < 32; i += 8)
    tile[ty + i][tx] = in[(size_t)(r0 + ty + i) * C + c0 + tx];
  __syncthreads();
#pragma unroll
  for (int i = 0; i < 32; i += 8)
    out[(size_t)(c0 + ty + i) * R + r0 + tx] = f2bf(tile[tx][ty + i]);
}

// ---------------- bf16 MFMA GEMM (round-14 proven: BK=64, slot-XOR swizzle) ----------------
template<int OUTF32>
__global__ __launch_bounds__(256, 2)
void gemm_bt(const unsigned short* __restrict__ A, const unsigned short* __restrict__ BT,
             const float* __restrict__ bias, void* __restrict__ outp,
             int M, int N, int K) {
  const int tid = threadIdx.x;
  const int w = tid >> 6, lane = tid & 63;
  const int lg = lane >> 4, l15 = lane & 15;
  const int wr = w >> 1, wc = w & 1;

  const int nb = gridDim.x * gridDim.y;
  const int fid = blockIdx.y * gridDim.x + blockIdx.x;
  const int swz = (fid & 7) * (nb >> 3) + (fid >> 3);
  const int n0 = (swz % gridDim.x) * 128, m0 = (swz / gridDim.x) * 128;

  __shared__ unsigned short As[128 * 64];
  __shared__ unsigned short Bs[128 * 64];

  f32x4 acc[4][4] = {};

  for (int k0 = 0; k0 < K; k0 += 64) {
    __syncthreads();
#pragma unroll
    for (int i = 0; i < 4; ++i) {
      const int cb = i * 256 + w * 64;
      const int c  = cb + lane;
      const int row = c >> 3, s = c & 7;
      const int sg = s ^ (row & 7);
      GLD16(A  + (size_t)(m0 + row) * K + k0 + sg * 8, (char*)As + cb * 16);
      GLD16(BT + (size_t)(n0 + row) * K + k0 + sg * 8, (char*)Bs + cb * 16);
    }
    __syncthreads();
#pragma unroll
    for (int ks = 0; ks < 2; ++ks) {
      bf16x8 af[4], bfr[4];
#pragma unroll
      for (int mt = 0; mt < 4; ++mt) {
        const int row = wr * 64 + mt * 16 + l15;
        af[mt] = *(const bf16x8*)&As[row * 64 + (((ks * 4 + lg) ^ (l15 & 7)) << 3)];
      }
#pragma unroll
      for (int nt = 0; nt < 4; ++nt) {
        const int row = wc * 64 + nt * 16 + l15;
        bfr[nt] = *(const bf16x8*)&Bs[row * 64 + (((ks * 4 + lg) ^ (l15 & 7)) << 3)];
      }
#pragma unroll
      for (int mt = 0; mt < 4; ++mt)
#pragma unroll
        for (int nt = 0; nt < 4; ++nt)
          acc[mt][nt] = __builtin_amdgcn_mfma_f32_16x16x32_bf16(af[mt], bfr[nt], acc[mt][nt], 0, 0, 0);
    }
  }

#pragma unroll
  for (int mt = 0; mt < 4; ++mt) {
#pragma unroll
    for (int nt = 0; nt < 4; ++nt) {
      const int col = n0 + wc * 64 + nt * 16 + l15;
      const float bv = bias[col];
#pragma unroll
      for (int j = 0; j < 4; ++j) {
        const int row = m0 + wr * 64 + mt * 16 + lg * 4 + j;
        const float v = acc[mt][nt][j] + bv;
        if (OUTF32) ((float*)outp)[(size_t)row * N + col] = v;
        else ((unsigned short*)outp)[(size_t)row * N + col] = f2bf(v);
      }
    }
  }
}

// ---------------- causal flash attention v12: v5 + triple-buffer + counted vmcnt ----------------
// v5 structure (8 waves x 16 q-rows, {p,15-p} pairing, 34 uniform iters) with
// prefetch depth 2: iter t issues K(t+2)+V(t+2) (3 vmem/wave), computes tile t,
// VWRITEs t+1, then waits vmcnt(3) (leaves exactly this iter's issues in flight)
// instead of __syncthreads' vmcnt(0) drain. FIFO: K(t+1)/V(t+1) are older than
// the 3 outstanding => provably landed. Static V-reg ping-pong via x2 unroll.
#define EXPC 0.18033688f   /* 0.125 * log2(e) */
__global__ __launch_bounds__(512, 4)
void attn_causal12(const unsigned short* __restrict__ qkv, unsigned short* __restrict__ att) {
  const int tid = threadIdx.x;
  const int w = tid >> 6, lane = tid & 63;
  const int lg = lane >> 4, l15 = lane & 15;

  const int fid = blockIdx.x;                   // 0..511
  const int f2 = (fid & 7) * 64 + (fid >> 3);   // XCD-chunked remap (bijective)
  const int pair = f2 & 7, bh = f2 >> 3;
  const int b = bh >> 4, h = bh & 15;

  __shared__ unsigned short Kl[3][2][64][32];   // 24 KB, slot+row permuted
  __shared__ unsigned short Vt[3][64][64];      // 24 KB, chunk-swizzled

  const unsigned short* base = qkv + (size_t)b * T_SEQ * 3072;

  auto STAGE_K = [&](int kv0, int buf) {
    const int c = tid;                          // 512 chunks of 16B, 1 gld_lds/thread
    const int kc = c >> 8, slot = (c >> 2) & 63;
    const int s2 = (c & 3) ^ ((slot >> 1) & 3);
    const int v = (slot & 35) | ((slot & 8) << 1) | ((slot & 4) << 1) | ((slot & 16) >> 2);
    GLD16(base + (size_t)(kv0 + v) * 3072 + 1024 + h * 64 + kc * 32 + s2 * 8,
          (char*)&Kl[buf][0][0][0] + w * 1024);
  };

  const int vkp = tid >> 4, vd4 = tid & 15;
  auto VLOAD = [&](int kv0, bf16x4& ra, bf16x4& rb) {   // 2 vmem/thread
    const unsigned short* p = base + (size_t)(kv0 + 2 * vkp) * 3072 + 2048 + h * 64 + vd4 * 4;
    ra = *(const bf16x4*)p;
    rb = *(const bf16x4*)(p + 3072);
  };
  auto VWRITE = [&](int buf, bf16x4 ra, bf16x4 rb) {
    const int ch = vkp >> 2, cl = (vkp & 3) * 2;
#pragma unroll
    for (int j = 0; j < 4; ++j) {
      const int r = vd4 * 4 + j;
      const unsigned int u = (unsigned short)ra[j] |
                             ((unsigned int)(unsigned short)rb[j] << 16);
      *(unsigned int*)&Vt[buf][r][((ch ^ (r >> 3) ^ (r & 7)) << 3) + cl] = u;
    }
  };

  bf16x8 ones;
#pragma unroll
  for (int j = 0; j < 8; ++j) ones[j] = (short)0x3F80;   // bf16 1.0

  for (int half = 0; half < 2; ++half) {
    const int qt = half ? (15 - pair) : pair;
    const int q0 = qt << 7;
    const int ntl = (qt + 1) << 1;              // KV64 tiles (always even, >= 2)
    const int qminS = __builtin_amdgcn_readfirstlane(q0 + w * 16);
    const int qme = qminS + l15;

    bf16x8 qf[2];
#pragma unroll
    for (int kc = 0; kc < 2; ++kc)
      qf[kc] = *(const bf16x8*)(base + (size_t)qme * 3072 + h * 64 + kc * 32 + lg * 8);

    f32x4 oacc[4] = {};
    f32x4 lsum = {};
    float m = -1e30f;
    bf16x4 v0a, v0b, v1a, v1b;                  // V-reg ping-pong: V(k) in set k&1

    auto COMPUTE = [&](int t, int bA) {
      const int kv0 = t << 6;
      if (kv0 > qminS + 15) return;             // wave fully masked (scalar)
      const int ksl = (lg ^ ((l15 >> 1) & 3)) * 8;
      f32x4 sc[4];
      __builtin_amdgcn_s_setprio(1);
#pragma unroll
      for (int kg = 0; kg < 4; ++kg) {
        f32x4 s = {};
#pragma unroll
        for (int kc = 0; kc < 2; ++kc) {
          bf16x8 kf = *(const bf16x8*)&Kl[bA][kc][kg * 16 + l15][ksl];
          s = __builtin_amdgcn_mfma_f32_16x16x32_bf16(kf, qf[kc], s, 0, 0, 0);
        }
        sc[kg] = s;
      }
      __builtin_amdgcn_s_setprio(0);

      float sv[4][4];
      if (kv0 + 63 > qminS) {
#pragma unroll
        for (int kg = 0; kg < 4; ++kg) {
          const int colb = kv0 + ((kg >> 1) << 5) + ((kg & 1) << 2) + lg * 8;
#pragma unroll
          for (int j = 0; j < 4; ++j)
            sv[kg][j] = (colb + j <= qme) ? sc[kg][j] : -1e30f;
        }
      } else {
#pragma unroll
        for (int kg = 0; kg < 4; ++kg)
#pragma unroll
          for (int j = 0; j < 4; ++j) sv[kg][j] = sc[kg][j];
      }

      float mx = -1e30f;
#pragma unroll
      for (int kg = 0; kg < 4; ++kg) {
        const float a = fmaxf(sv[kg][0], sv[kg][1]);
        const float c2 = fmaxf(sv[kg][2], sv[kg][3]);
        mx = fmaxf(mx, fmaxf(a, c2));
      }

      if (__any(mx > m + 55.4f)) {
        float mw = fmaxf(mx, __shfl_xor(mx, 16));
        mw = fmaxf(mw, __shfl_xor(mw, 32));
        const float mnew = fmaxf(m, mw);
        const float alc = exp2f((m - mnew) * EXPC);
        m = mnew;
        float alq[4];
#pragma unroll
        for (int j = 0; j < 4; ++j)
          alq[j] = __shfl(alc, (lane & 48) | (lg * 4 + j));
#pragma unroll
        for (int j = 0; j < 4; ++j) {
          lsum[j] *= alq[j];
#pragma unroll
          for (int dt = 0; dt < 4; ++dt) oacc[dt][j] *= alq[j];
        }
      }

      const float mc = m * EXPC;
      bf16x8 pa[2];
#pragma unroll
      for (int kg = 0; kg < 4; ++kg) {
        const int ks = kg >> 1, off = (kg & 1) * 4;
#pragma unroll
        for (int j = 0; j < 4; ++j) {
          const float p = exp2f(__fmaf_rn(sv[kg][j], EXPC, -mc));
          pa[ks][off + j] = (short)f2bf(p);
        }
      }

      __builtin_amdgcn_s_setprio(1);
      lsum = __builtin_amdgcn_mfma_f32_16x16x32_bf16(pa[0], ones, lsum, 0, 0, 0);
      lsum = __builtin_amdgcn_mfma_f32_16x16x32_bf16(pa[1], ones, lsum, 0, 0, 0);
#pragma unroll
      for (int dt = 0; dt < 4; ++dt) {
        f32x4 o = oacc[dt];
        const int d = dt * 16 + l15;
        const int gx = (d >> 3) ^ (d & 7);
#pragma unroll
        for (int ks = 0; ks < 2; ++ks) {
          bf16x8 vb = *(const bf16x8*)&Vt[bA][d][((ks * 4 + lg) ^ gx) << 3];
          o = __builtin_amdgcn_mfma_f32_16x16x32_bf16(pa[ks], vb, o, 0, 0, 0);
        }
        oacc[dt] = o;
      }
      __builtin_amdgcn_s_setprio(0);
    };

    auto TAIL = [&](int t, int bB, bf16x4 wa, bf16x4 wb) {
      if ((t + 1) < ntl) VWRITE(bB, wa, wb);    // compiler drains V(t+1) loads (older than this iter's 3)
      if ((t + 2) < ntl) {                      // this iter issued 3 vmem: leave them in flight
        asm volatile("s_waitcnt vmcnt(3) lgkmcnt(0)" ::: "memory");
      } else {                                  // no prefetch this iter: full drain
        asm volatile("s_waitcnt vmcnt(0) lgkmcnt(0)" ::: "memory");
      }
      __builtin_amdgcn_sched_barrier(0);
      __builtin_amdgcn_s_barrier();
      __builtin_amdgcn_sched_barrier(0);
    };

    // ---- prologue: tiles 0 and 1 ----
    STAGE_K(0, 0);
    VLOAD(0, v0a, v0b);
    VWRITE(0, v0a, v0b);                        // reg-dep drains K(0)+V(0)
    STAGE_K(64, 1);
    VLOAD(64, v1a, v1b);
    asm volatile("s_waitcnt vmcnt(3) lgkmcnt(0)" ::: "memory");  // K(1),V(1) stay in flight
    __builtin_amdgcn_sched_barrier(0);
    __builtin_amdgcn_s_barrier();
    __builtin_amdgcn_sched_barrier(0);

    int bA = 0, bB = 1, bC = 2;
    for (int t = 0; t < ntl; t += 2) {
      if ((t + 2) < ntl) { STAGE_K((t + 2) << 6, bC); VLOAD((t + 2) << 6, v0a, v0b); }
      COMPUTE(t, bA);
      TAIL(t, bB, v1a, v1b);                    // VWRITE(t+1) from set1
      if ((t + 3) < ntl) { STAGE_K((t + 3) << 6, bA); VLOAD((t + 3) << 6, v1a, v1b); }
      COMPUTE(t + 1, bB);
      TAIL(t + 1, bC, v0a, v0b);                // VWRITE(t+2) from set0
      const int nA = bC, nB2 = bA, nC = bB;     // rotate by 2: (A,B,C) <- (C,A,B)
      bA = nA; bB = nB2; bC = nC;
    }

    // ---- epilogue: normalize via rcp, store ----
    f32x4 inv;
#pragma unroll
    for (int j = 0; j < 4; ++j) inv[j] = __builtin_amdgcn_rcpf(lsum[j]);
#pragma unroll
    for (int dt = 0; dt < 4; ++dt)
#pragma unroll
      for (int j = 0; j < 4; ++j) {
        const int q = qminS + lg * 4 + j;
        att[(size_t)(b * T_SEQ + q) * CDIM + h * HDIM + dt * 16 + l15] =
            f2bf(oacc[dt][j] * inv[j]);
      }
  }
}

// ---------------- launcher ----------------
extern "C" void kernel_launch(void* const* d_in, const int* in_sizes, int n_in,
                              void* d_out, int out_size, void* d_ws, size_t ws_size,
                              hipStream_t stream) {
  const float* x      = (const float*)d_in[0];
  const float* w_attn = (const float*)d_in[1];
  const float* b_attn = (const float*)d_in[2];
  const float* w_proj = (const float*)d_in[3];
  const float* b_proj = (const float*)d_in[4];

  char* ws = (char*)d_ws;
  unsigned short* xb  = (unsigned short*)(ws + 0);           // 8192*1024 bf16
  unsigned short* wat = (unsigned short*)(ws + 16777216);    // 3072*1024 bf16 (w_attn^T)
  unsigned short* wpt = (unsigned short*)(ws + 23068672);    // 1024*1024 bf16 (w_proj^T)
  unsigned short* qkv = (unsigned short*)(ws + 25165824);    // 8192*3072 bf16
  unsigned short* att = (unsigned short*)(ws + 75497472);    // 8192*1024 bf16

  prep_all<<<dim3(12288), 256, 0, stream>>>(x, w_attn, w_proj, xb, wat, wpt);
  gemm_bt<0><<<dim3(24, 64), 256, 0, stream>>>(xb, wat, b_attn, (void*)qkv, 8192, 3072, 1024);
  attn_causal12<<<dim3(512), 512, 0, stream>>>(qkv, att);
  gemm_bt<1><<<dim3(8, 64), 256, 0, stream>>>(att, wpt, b_proj, d_out, 8192, 1024, 1024);
}

// Round 17
// 172.356 us; speedup vs baseline: 1.0067x; 1.0057x over previous
//
#include <hip/hip_runtime.h>
#include <hip/hip_bf16.h>

#define T_SEQ 2048
#define NHEAD 16
#define HDIM  64
#define CDIM  1024

typedef __attribute__((ext_vector_type(8))) short bf16x8;
typedef __attribute__((ext_vector_type(4))) short bf16x4;
typedef __attribute__((ext_vector_type(4))) float f32x4;

__device__ __forceinline__ unsigned short f2bf(float f) {
  union { __hip_bfloat16 h; unsigned short u; } c;
  c.h = __float2bfloat16(f);
  return c.u;
}

#define GLD16(g, l) __builtin_amdgcn_global_load_lds( \
  (const __attribute__((address_space(1))) void*)(g), \
  (__attribute__((address_space(3))) void*)(l), 16, 0, 0)

// ---------------- merged prep: x->bf16 cast + both weight transposes ----------------
// blocks [0,8192): cvt x (float4 each);  [8192,11264): w_attn^T;  [11264,12288): w_proj^T
__global__ void prep_all(const float* __restrict__ x, const float* __restrict__ wa,
                         const float* __restrict__ wp, unsigned short* __restrict__ xb,
                         unsigned short* __restrict__ wat, unsigned short* __restrict__ wpt) {
  __shared__ float tile[32][33];
  const int bid = blockIdx.x;
  if (bid < 8192) {
    const int i = bid * 256 + threadIdx.x;
    const float4 v = ((const float4*)x)[i];
    ushort4 o;
    o.x = f2bf(v.x); o.y = f2bf(v.y); o.z = f2bf(v.z); o.w = f2bf(v.w);
    ((ushort4*)xb)[i] = o;
    return;
  }
  const float* in; unsigned short* out; int R, C, bx, by;
  if (bid < 11264) { in = wa; out = wat; R = 1024; C = 3072; bx = (bid - 8192) % 96; by = (bid - 8192) / 96; }
  else             { in = wp; out = wpt; R = 1024; C = 1024; bx = (bid - 11264) % 32; by = (bid - 11264) / 32; }
  const int tx = threadIdx.x & 31, ty = threadIdx.x >> 5;
  const int c0 = bx * 32, r0 = by * 32;
#pragma unroll
  for (int i = 0; i < 32; i += 8)
    tile[ty + i][tx] = in[(size_t)(r0 + ty + i) * C + c0 + tx];
  __syncthreads();
#pragma unroll
  for (int i = 0; i < 32; i += 8)
    out[(size_t)(c0 + ty + i) * R + r0 + tx] = f2bf(tile[tx][ty + i]);
}

// ---------------- bf16 MFMA GEMM: C[M][N] = A[M][K] * BT[N][K]^T + bias ----------------
// 128x128 tile, BK=64 (half the barrier-drain events of BK=32), 4 waves (2x2).
// LDS slot-XOR swizzle: stage fetches global slot s^(row&7) into phys slot s;
// frag reads use phys = (ks*4+lg)^(l15&7) -> measured 0 bank conflicts. XCD-chunked swizzle.
template<int OUTF32>
__global__ __launch_bounds__(256, 2)
void gemm_bt(const unsigned short* __restrict__ A, const unsigned short* __restrict__ BT,
             const float* __restrict__ bias, void* __restrict__ outp,
             int M, int N, int K) {
  const int tid = threadIdx.x;
  const int w = tid >> 6, lane = tid & 63;
  const int lg = lane >> 4, l15 = lane & 15;
  const int wr = w >> 1, wc = w & 1;

  const int nb = gridDim.x * gridDim.y;
  const int fid = blockIdx.y * gridDim.x + blockIdx.x;
  const int swz = (fid & 7) * (nb >> 3) + (fid >> 3);
  const int n0 = (swz % gridDim.x) * 128, m0 = (swz / gridDim.x) * 128;

  __shared__ unsigned short As[128 * 64];
  __shared__ unsigned short Bs[128 * 64];

  f32x4 acc[4][4] = {};

  for (int k0 = 0; k0 < K; k0 += 64) {
    __syncthreads();
#pragma unroll
    for (int i = 0; i < 4; ++i) {
      const int cb = i * 256 + w * 64;   // wave-uniform chunk base
      const int c  = cb + lane;
      const int row = c >> 3, s = c & 7;
      const int sg = s ^ (row & 7);      // pre-swizzled source slot
      GLD16(A  + (size_t)(m0 + row) * K + k0 + sg * 8, (char*)As + cb * 16);
      GLD16(BT + (size_t)(n0 + row) * K + k0 + sg * 8, (char*)Bs + cb * 16);
    }
    __syncthreads();
#pragma unroll
    for (int ks = 0; ks < 2; ++ks) {
      bf16x8 af[4], bfr[4];
#pragma unroll
      for (int mt = 0; mt < 4; ++mt) {
        const int row = wr * 64 + mt * 16 + l15;
        af[mt] = *(const bf16x8*)&As[row * 64 + (((ks * 4 + lg) ^ (l15 & 7)) << 3)];
      }
#pragma unroll
      for (int nt = 0; nt < 4; ++nt) {
        const int row = wc * 64 + nt * 16 + l15;
        bfr[nt] = *(const bf16x8*)&Bs[row * 64 + (((ks * 4 + lg) ^ (l15 & 7)) << 3)];
      }
#pragma unroll
      for (int mt = 0; mt < 4; ++mt)
#pragma unroll
        for (int nt = 0; nt < 4; ++nt)
          acc[mt][nt] = __builtin_amdgcn_mfma_f32_16x16x32_bf16(af[mt], bfr[nt], acc[mt][nt], 0, 0, 0);
    }
  }

#pragma unroll
  for (int mt = 0; mt < 4; ++mt) {
#pragma unroll
    for (int nt = 0; nt < 4; ++nt) {
      const int col = n0 + wc * 64 + nt * 16 + l15;
      const float bv = bias[col];
#pragma unroll
      for (int j = 0; j < 4; ++j) {
        const int row = m0 + wr * 64 + mt * 16 + lg * 4 + j;
        const float v = acc[mt][nt][j] + bv;
        if (OUTF32) ((float*)outp)[(size_t)row * N + col] = v;
        else ((unsigned short*)outp)[(size_t)row * N + col] = f2bf(v);
      }
    }
  }
}

// ---------------- causal flash attention (v5 exact, proven 87.2 us) ----------------
// 512 threads = 8 waves x 16 q-rows; in-block pairing {p,15-p}: uniform 34 KV64 iters.
// K rows bit-permuted in LDS so swapped-QK^T output == PV A-fragment (reg-only P);
// lsum via ones-MFMA in O layout; scalarized mask; K slot swizzle; V chunk swizzle.
#define EXPC 0.18033688f   /* 0.125 * log2(e) */
__global__ __launch_bounds__(512, 4)
void attn_causal5(const unsigned short* __restrict__ qkv, unsigned short* __restrict__ att) {
  const int tid = threadIdx.x;
  const int w = tid >> 6, lane = tid & 63;
  const int lg = lane >> 4, l15 = lane & 15;

  const int fid = blockIdx.x;                   // 0..511
  const int f2 = (fid & 7) * 64 + (fid >> 3);   // XCD-chunked remap (bijective)
  const int pair = f2 & 7, bh = f2 >> 3;
  const int b = bh >> 4, h = bh & 15;

  __shared__ unsigned short Kl[2][2][64][32];   // [buf][kc][ldsrow][el], slot+row permuted
  __shared__ unsigned short Vt[2][64][64];      // [buf][d][kv], chunk-swizzled

  const unsigned short* base = qkv + (size_t)b * T_SEQ * 3072;

  auto STAGE_K = [&](int kv0, int buf) {
    const int c = tid;                          // 512 chunks of 16B
    const int kc = c >> 8, slot = (c >> 2) & 63;
    const int s2 = (c & 3) ^ ((slot >> 1) & 3);
    const int v = (slot & 35) | ((slot & 8) << 1) | ((slot & 4) << 1) | ((slot & 16) >> 2);
    GLD16(base + (size_t)(kv0 + v) * 3072 + 1024 + h * 64 + kc * 32 + s2 * 8,
          (char*)&Kl[buf][0][0][0] + w * 1024);
  };

  bf16x4 vra, vrb;
  const int vkp = tid >> 4, vd4 = tid & 15;
  auto VLOAD = [&](int kv0) {
    const unsigned short* p = base + (size_t)(kv0 + 2 * vkp) * 3072 + 2048 + h * 64 + vd4 * 4;
    vra = *(const bf16x4*)p;
    vrb = *(const bf16x4*)(p + 3072);
  };
  auto VWRITE = [&](int buf) {
    const int ch = vkp >> 2, cl = (vkp & 3) * 2;
#pragma unroll
    for (int j = 0; j < 4; ++j) {
      const int r = vd4 * 4 + j;
      const unsigned int u = (unsigned short)vra[j] |
                             ((unsigned int)(unsigned short)vrb[j] << 16);
      *(unsigned int*)&Vt[buf][r][((ch ^ (r >> 3) ^ (r & 7)) << 3) + cl] = u;
    }
  };

  bf16x8 ones;
#pragma unroll
  for (int j = 0; j < 8; ++j) ones[j] = (short)0x3F80;   // bf16 1.0

  for (int half = 0; half < 2; ++half) {
    const int qt = half ? (15 - pair) : pair;
    const int q0 = qt << 7;
    const int ntl = (qt + 1) << 1;              // KV64 tiles
    const int qminS = __builtin_amdgcn_readfirstlane(q0 + w * 16);
    const int qme = qminS + l15;

    bf16x8 qf[2];
#pragma unroll
    for (int kc = 0; kc < 2; ++kc)
      qf[kc] = *(const bf16x8*)(base + (size_t)qme * 3072 + h * 64 + kc * 32 + lg * 8);

    f32x4 oacc[4] = {};
    f32x4 lsum = {};
    float m = -1e30f;

    STAGE_K(0, 0);
    VLOAD(0);
    VWRITE(0);
    __syncthreads();

    for (int t = 0; t < ntl; ++t) {
      const int cur = t & 1, nxt = cur ^ 1;
      const bool pf = (t + 1) < ntl;
      if (pf) { STAGE_K((t + 1) << 6, nxt); VLOAD((t + 1) << 6); }
      const int kv0 = t << 6;

      if (kv0 <= qminS + 15) {                  // wave has unmasked work
        const int ksl = (lg ^ ((l15 >> 1) & 3)) * 8;
        f32x4 sc[4];
        __builtin_amdgcn_s_setprio(1);
#pragma unroll
        for (int kg = 0; kg < 4; ++kg) {
          f32x4 s = {};
#pragma unroll
          for (int kc = 0; kc < 2; ++kc) {
            bf16x8 kf = *(const bf16x8*)&Kl[cur][kc][kg * 16 + l15][ksl];
            s = __builtin_amdgcn_mfma_f32_16x16x32_bf16(kf, qf[kc], s, 0, 0, 0);
          }
          sc[kg] = s;
        }
        __builtin_amdgcn_s_setprio(0);

        // ---- mask (diagonal tiles only, scalar-guarded) ----
        float sv[4][4];
        if (kv0 + 63 > qminS) {
#pragma unroll
          for (int kg = 0; kg < 4; ++kg) {
            const int colb = kv0 + ((kg >> 1) << 5) + ((kg & 1) << 2) + lg * 8;
#pragma unroll
            for (int j = 0; j < 4; ++j)
              sv[kg][j] = (colb + j <= qme) ? sc[kg][j] : -1e30f;
          }
        } else {
#pragma unroll
          for (int kg = 0; kg < 4; ++kg)
#pragma unroll
            for (int j = 0; j < 4; ++j) sv[kg][j] = sc[kg][j];
        }

        // ---- tree max ----
        float mx = -1e30f;
#pragma unroll
        for (int kg = 0; kg < 4; ++kg) {
          const float a = fmaxf(sv[kg][0], sv[kg][1]);
          const float c2 = fmaxf(sv[kg][2], sv[kg][3]);
          mx = fmaxf(mx, fmaxf(a, c2));
        }

        // ---- defer-max rescale (rare) ----
        if (__any(mx > m + 55.4f)) {
          float mw = fmaxf(mx, __shfl_xor(mx, 16));
          mw = fmaxf(mw, __shfl_xor(mw, 32));
          const float mnew = fmaxf(m, mw);
          const float alc = exp2f((m - mnew) * EXPC);
          m = mnew;
          float alq[4];
#pragma unroll
          for (int j = 0; j < 4; ++j)
            alq[j] = __shfl(alc, (lane & 48) | (lg * 4 + j));
#pragma unroll
          for (int j = 0; j < 4; ++j) {
            lsum[j] *= alq[j];
#pragma unroll
            for (int dt = 0; dt < 4; ++dt) oacc[dt][j] *= alq[j];
          }
        }

        // ---- exp -> PV A-fragments (registers, same lane) ----
        const float mc = m * EXPC;
        bf16x8 pa[2];
#pragma unroll
        for (int kg = 0; kg < 4; ++kg) {
          const int ks = kg >> 1, off = (kg & 1) * 4;
#pragma unroll
          for (int j = 0; j < 4; ++j) {
            const float p = exp2f(__fmaf_rn(sv[kg][j], EXPC, -mc));
            pa[ks][off + j] = (short)f2bf(p);
          }
        }

        // ---- lsum via ones-MFMA + PV ----
        __builtin_amdgcn_s_setprio(1);
        lsum = __builtin_amdgcn_mfma_f32_16x16x32_bf16(pa[0], ones, lsum, 0, 0, 0);
        lsum = __builtin_amdgcn_mfma_f32_16x16x32_bf16(pa[1], ones, lsum, 0, 0, 0);
#pragma unroll
        for (int dt = 0; dt < 4; ++dt) {
          f32x4 o = oacc[dt];
          const int d = dt * 16 + l15;
          const int gx = (d >> 3) ^ (d & 7);    // V chunk swizzle
#pragma unroll
          for (int ks = 0; ks < 2; ++ks) {
            bf16x8 vb = *(const bf16x8*)&Vt[cur][d][((ks * 4 + lg) ^ gx) << 3];
            o = __builtin_amdgcn_mfma_f32_16x16x32_bf16(pa[ks], vb, o, 0, 0, 0);
          }
          oacc[dt] = o;
        }
        __builtin_amdgcn_s_setprio(0);
      }

      if (pf) VWRITE(nxt);
      __syncthreads();   // drains vmcnt (K gld_lds) + lgkm (V writes); swap buffers
    }

    // ---- epilogue: normalize via rcp, store ----
    f32x4 inv;
#pragma unroll
    for (int j = 0; j < 4; ++j) inv[j] = __builtin_amdgcn_rcpf(lsum[j]);
#pragma unroll
    for (int dt = 0; dt < 4; ++dt)
#pragma unroll
      for (int j = 0; j < 4; ++j) {
        const int q = qminS + lg * 4 + j;
        att[(size_t)(b * T_SEQ + q) * CDIM + h * HDIM + dt * 16 + l15] =
            f2bf(oacc[dt][j] * inv[j]);
      }
  }
}

// ---------------- launcher ----------------
extern "C" void kernel_launch(void* const* d_in, const int* in_sizes, int n_in,
                              void* d_out, int out_size, void* d_ws, size_t ws_size,
                              hipStream_t stream) {
  const float* x      = (const float*)d_in[0];
  const float* w_attn = (const float*)d_in[1];
  const float* b_attn = (const float*)d_in[2];
  const float* w_proj = (const float*)d_in[3];
  const float* b_proj = (const float*)d_in[4];

  char* ws = (char*)d_ws;
  unsigned short* xb  = (unsigned short*)(ws + 0);           // 8192*1024 bf16
  unsigned short* wat = (unsigned short*)(ws + 16777216);    // 3072*1024 bf16 (w_attn^T)
  unsigned short* wpt = (unsigned short*)(ws + 23068672);    // 1024*1024 bf16 (w_proj^T)
  unsigned short* qkv = (unsigned short*)(ws + 25165824);    // 8192*3072 bf16
  unsigned short* att = (unsigned short*)(ws + 75497472);    // 8192*1024 bf16

  prep_all<<<dim3(12288), 256, 0, stream>>>(x, w_attn, w_proj, xb, wat, wpt);
  gemm_bt<0><<<dim3(24, 64), 256, 0, stream>>>(xb, wat, b_attn, (void*)qkv, 8192, 3072, 1024);
  attn_causal5<<<dim3(512), 512, 0, stream>>>(qkv, att);
  gemm_bt<1><<<dim3(8, 64), 256, 0, stream>>>(att, wpt, b_proj, d_out, 8192, 1024, 1024);
}